// Round 11
// baseline (1626.097 us; speedup 1.0000x reference)
//
#include <hip/hip_runtime.h>
#include <hip/hip_bf16.h>

#define Bn 32
#define Sn 400
#define Tn 100
#define Vn 32000
#define OOVn 100
#define VEn 32100
#define En 512
#define Un 256
#define AUn 256
#define GPn 256
#define ENCn 512
#define Z4n 1024

typedef __attribute__((ext_vector_type(8))) short bf16x8;
typedef __attribute__((ext_vector_type(4))) float f32x4;
typedef unsigned short ushort_t;
typedef unsigned long long u64;

__device__ __forceinline__ float rcp_f(float x){ return __builtin_amdgcn_rcpf(x); }
__device__ __forceinline__ float tanh_fast(float x){
  float e2 = __expf(2.f*x);
  return 1.f - 2.f*rcp_f(e2 + 1.f);
}
__device__ __forceinline__ float sigmoid_f(float x){ return 1.f/(1.f+__expf(-x)); }
__device__ __forceinline__ ushort_t f2bf(float f){
  unsigned u = __float_as_uint(f);
  unsigned r = (u + 0x7FFFu + ((u>>16)&1u)) >> 16;   // RNE
  return (ushort_t)r;
}
__device__ __forceinline__ u64 shfl_xor_u64(u64 v, int m){
  unsigned lo = (unsigned)v, hi = (unsigned)(v>>32);
  lo = (unsigned)__shfl_xor((int)lo, m);
  hi = (unsigned)__shfl_xor((int)hi, m);
  return ((u64)hi<<32)|(u64)lo;
}

// relaxed agent-scope ops: coherence-point loads/stores, no cache maintenance
__device__ __forceinline__ void st_rlx(float* p, float v){
  __hip_atomic_store(p, v, __ATOMIC_RELAXED, __HIP_MEMORY_SCOPE_AGENT);
}
__device__ __forceinline__ float ld_rlx(const float* p){
  return __hip_atomic_load(p, __ATOMIC_RELAXED, __HIP_MEMORY_SCOPE_AGENT);
}
__device__ __forceinline__ void st_flag(unsigned* p, unsigned v){
  __hip_atomic_store(p, v, __ATOMIC_RELAXED, __HIP_MEMORY_SCOPE_AGENT);
}
__device__ __forceinline__ unsigned ld_flag(const unsigned* p){
  return __hip_atomic_load(p, __ATOMIC_RELAXED, __HIP_MEMORY_SCOPE_AGENT);
}

// ---------------- pre-loop kernels ----------------

__global__ __launch_bounds__(256) void k_gather(const int* __restrict__ gt,
    const float* __restrict__ emb, float* __restrict__ Xall){
  int r = blockIdx.x;                 // r = t*32 + b
  int t = r >> 5, b = r & 31;
  int tok = gt[b*Tn + t];
  const float* src = emb + (size_t)tok*En;
  float* dst = Xall + (size_t)r*En;
  for (int i = threadIdx.x; i < En; i += 256) dst[i] = src[i];
}

// Zx = Xall @ Wk + bias   [3200,512]@[512,1024], f32 tiled 64x64 (round-8 form)
__global__ __launch_bounds__(256) void k_zx(const float* __restrict__ X,
    const float* __restrict__ Wk, const float* __restrict__ bias, float* __restrict__ Zx){
  __shared__ float As[64][17];
  __shared__ float Bs[16][65];
  int r0 = blockIdx.x * 64;
  int c0 = blockIdx.y * 64;
  int tid = threadIdx.x;
  int ty = tid >> 4, tx = tid & 15;
  float acc[4][4] = {};
  for (int k0 = 0; k0 < En; k0 += 16){
    #pragma unroll
    for (int p = 0; p < 4; ++p){
      int row = (tid>>4) + p*16, kk = tid & 15;
      As[row][kk] = X[(size_t)(r0+row)*En + k0 + kk];
    }
    #pragma unroll
    for (int p = 0; p < 4; ++p){
      int kk = (tid>>6) + p*4, cc = tid & 63;
      Bs[kk][cc] = Wk[(size_t)(k0+kk)*Z4n + c0 + cc];
    }
    __syncthreads();
    #pragma unroll
    for (int kk = 0; kk < 16; ++kk){
      float av[4], bv[4];
      #pragma unroll
      for (int i=0;i<4;++i) av[i] = As[ty*4+i][kk];
      #pragma unroll
      for (int j=0;j<4;++j) bv[j] = Bs[kk][tx*4+j];
      #pragma unroll
      for (int i=0;i<4;++i)
        #pragma unroll
        for (int j=0;j<4;++j) acc[i][j] += av[i]*bv[j];
    }
    __syncthreads();
  }
  #pragma unroll
  for (int i=0;i<4;++i){
    int row = r0 + ty*4 + i;
    #pragma unroll
    for (int j=0;j<4;++j){
      int col = c0 + tx*4 + j;
      Zx[(size_t)row*Z4n + col] = acc[i][j] + bias[col];
    }
  }
}

// gpx[t,:] = x[t,b=0,:] @ gp_Wi + gp_bi
__global__ __launch_bounds__(256) void k_gpx(const float* __restrict__ Xall,
    const float* __restrict__ Wi, const float* __restrict__ bi, float* __restrict__ gpx){
  int t = blockIdx.x, j = threadIdx.x;
  const float* x = Xall + (size_t)(t*Bn + 0)*En;
  float acc = bi[j];
  for (int u = 0; u < En; ++u) acc += x[u]*Wi[u*GPn + j];
  gpx[t*GPn + j] = acc;
}

// W2 [256][32000] f32 -> W2T [32000][256] bf16 (LDS-tiled transpose)
__global__ __launch_bounds__(256) void k_w2t(const float* __restrict__ W2,
    ushort_t* __restrict__ W2T){
  __shared__ float tile[64][65];
  int n0 = blockIdx.x * 64;   // 500
  int k0 = blockIdx.y * 64;   // 4
  int tx = threadIdx.x & 63, ty4 = threadIdx.x >> 6;
  #pragma unroll
  for (int i = 0; i < 16; ++i){
    int k = ty4 + i*4;
    tile[k][tx] = W2[(size_t)(k0+k)*Vn + n0 + tx];
  }
  __syncthreads();
  #pragma unroll
  for (int i = 0; i < 16; ++i){
    int n = ty4 + i*4;
    W2T[(size_t)(n0+n)*Un + k0 + tx] = f2bf(tile[tx][n]);
  }
}

// ---------------- persistent 256-block recurrent kernel ----------------
// b = blockIdx&31, k = blockIdx>>5. ONE flag/step, 4 barriers/step.
// Waves 0-7: in-wave LSTM (no partial-combine barrier): wave w owns cols
//   i = 4w..4w+3; 16 lanes/col = 4 gate-comps x 4 u-parts; shfl reduce+gather.
// Waves 8-15: attention rows r%8==w-8 held ENTIRELY in registers (cov, exp)
//   across steps: finalize(t-1) + scores(t) + spart publish, no barriers.
// Wr LDS layout [i][comp][part][68], i-stride 1092 floats (bank-spread, 16B-aligned).

__global__ __launch_bounds__(1024, 1) void k_loop(
    const float* __restrict__ Zx, const float* __restrict__ Wr,
    const float* __restrict__ Wd, const float* __restrict__ bd,
    const float* __restrict__ Wc, const float* __restrict__ Wa,
    const float* __restrict__ enc_attn,
    const float* __restrict__ h0, const float* __restrict__ c0,
    float* __restrict__ h_all, float* __restrict__ decp,
    float* __restrict__ c0_all, float* __restrict__ a_all,
    float* __restrict__ covloss, float* __restrict__ spart2,
    unsigned* __restrict__ bars){
  __shared__ float Wr4[32*1092];      // ~136.5 KB
  __shared__ float hfull[Un];
  __shared__ float zx_lds[128];
  __shared__ float hnew[32], cown[32];
  __shared__ float dec_lds[AUn];
  __shared__ float red64[64];

  const int b = blockIdx.x & 31, k = blockIdx.x >> 5;
  const int tid = threadIdx.x, lane = tid & 63, w = tid >> 6;
  unsigned* flags = bars + b*8*32;          // 8 slots, 128 B apart
  unsigned* myflag = flags + k*32;

  // ---- init: Wr slice into blocked layout ----
  for (int idx = tid; idx < 32768; idx += 1024){
    int i    = idx & 31;
    int up   = (idx >> 5) & 63;
    int part = (idx >> 11) & 3;
    int comp = (idx >> 13) & 3;
    int u = part*64 + up;
    int gcol = comp*256 + 32*k + i;
    Wr4[i*1092 + (comp*4 + part)*68 + up] = Wr[(size_t)u*Z4n + gcol];
  }
  if (tid < 32) cown[tid] = c0[b*Un + 32*k + tid];
  const float4 wc4 = *(const float4*)(Wc + lane*4);
  const float4 wa4 = *(const float4*)(Wa + lane*4);
  if (tid < 256) hfull[tid] = h0[b*Un + tid];
  if (tid >= 256 && tid < 384){
    int jl = tid - 256;
    int gcol = 32*k + (jl & 31) + 256*(jl >> 5);
    zx_lds[jl] = Zx[(size_t)(0*Bn + b)*Z4n + gcol];
  }
  // per-row attention state in registers (waves 8-15)
  float cov_r[7] = {0.f,0.f,0.f,0.f,0.f,0.f,0.f};
  float ev_r[7]  = {0.f,0.f,0.f,0.f,0.f,0.f,0.f};
  __syncthreads();

  // ======== prestep: h(0), c(0), decp slot0, flag = 1 ========
  if (w < 8){
    int ci = lane >> 4;
    int i  = w*4 + ci;
    int comp = (lane >> 2) & 3;
    int part = lane & 3;
    const float* wrp = Wr4 + i*1092 + (comp*4 + part)*68;
    const float* hp  = hfull + part*64;
    float acc = 0.f;
    #pragma unroll
    for (int c = 0; c < 16; ++c){
      float4 wv = *(const float4*)(wrp + 4*c);
      float4 hv = *(const float4*)(hp + 4*c);
      acc += wv.x*hv.x + wv.y*hv.y + wv.z*hv.z + wv.w*hv.w;
    }
    acc += __shfl_xor(acc, 1);
    acc += __shfl_xor(acc, 2);
    int b16 = lane & 48;
    float zi = __shfl(acc, b16+0)  + zx_lds[i];
    float zf = __shfl(acc, b16+4)  + zx_lds[32+i];
    float zg = __shfl(acc, b16+8)  + zx_lds[64+i];
    float zo = __shfl(acc, b16+12) + zx_lds[96+i];
    float cn = sigmoid_f(zf)*cown[i] + sigmoid_f(zi)*tanhf(zg);
    float hn = sigmoid_f(zo)*tanhf(cn);
    if ((lane & 15) == 0){
      cown[i] = cn; hnew[i] = hn;
      int col = 32*k + i;
      st_rlx(h_all + (size_t)(0*Bn + b)*Un + col, hn);
      if (b == 0) c0_all[0*Un + col] = cn;
    }
  }
  __syncthreads();
  if (tid < 256){
    int c = tid;
    float acc = 0.f;
    const float* wdh = Wd + (size_t)(32*k)*AUn + c;
    #pragma unroll 8
    for (int u = 0; u < 32; ++u) acc += hnew[u]*wdh[(size_t)u*AUn];
    const float* wdc = Wd + (size_t)(Un + 32*k)*AUn + c;
    #pragma unroll 8
    for (int u = 0; u < 32; ++u) acc += cown[u]*wdc[(size_t)u*AUn];
    st_rlx(decp + (size_t)(b*8 + k)*256 + c, acc);   // slot 0
  }
  __syncthreads();    // drains vmcnt
  if (tid == 0) st_flag(myflag, 1u);

  // ======== main loop ========
  for (int t = 0; t < Tn; ++t){
    const int cur = t & 1, oth = cur ^ 1;
    // P0: wait (h(t), decp[cur], spart2[oth](t-1) all published)
    if (tid < 8){
      while (ld_flag(flags + tid*32) < (unsigned)(t+1))
        __builtin_amdgcn_s_sleep(1);
    }
    __syncthreads();
    // P1: consolidated cross-block loads
    if (tid < 256){
      hfull[tid] = ld_rlx(h_all + (size_t)(t*Bn + b)*Un + tid);
    } else if (tid < 512){
      int c = tid - 256;
      float s = bd[c];
      const float* dp = decp + (size_t)cur*(Bn*8*256) + (size_t)(b*8)*256 + c;
      #pragma unroll
      for (int q = 0; q < 8; ++q) s += ld_rlx(dp + q*256);
      dec_lds[c] = s;
    } else if (tid < 576){
      red64[tid-512] = (t > 0) ? ld_rlx(spart2 + oth*(Bn*64) + b*64 + (tid-512)) : 0.f;
    } else if (tid >= 640 && tid < 768 && t + 1 < Tn){
      int jl = tid - 640;
      int gcol = 32*k + (jl & 31) + 256*(jl >> 5);
      zx_lds[jl] = Zx[(size_t)((t+1)*Bn + b)*Z4n + gcol];
    }
    __syncthreads();
    // P2: waves 0-7 in-wave LSTM(t+1) || waves 8-15 finalize(t-1)+scores(t)
    if (w < 8){
      if (t + 1 < Tn){
        int ci = lane >> 4;
        int i  = w*4 + ci;
        int comp = (lane >> 2) & 3;
        int part = lane & 3;
        const float* wrp = Wr4 + i*1092 + (comp*4 + part)*68;
        const float* hp  = hfull + part*64;
        float acc = 0.f;
        #pragma unroll
        for (int c = 0; c < 16; ++c){
          float4 wv = *(const float4*)(wrp + 4*c);
          float4 hv = *(const float4*)(hp + 4*c);
          acc += wv.x*hv.x + wv.y*hv.y + wv.z*hv.z + wv.w*hv.w;
        }
        acc += __shfl_xor(acc, 1);
        acc += __shfl_xor(acc, 2);
        int b16 = lane & 48;
        float zi = __shfl(acc, b16+0)  + zx_lds[i];
        float zf = __shfl(acc, b16+4)  + zx_lds[32+i];
        float zg = __shfl(acc, b16+8)  + zx_lds[64+i];
        float zo = __shfl(acc, b16+12) + zx_lds[96+i];
        float cn = sigmoid_f(zf)*cown[i] + sigmoid_f(zi)*tanhf(zg);
        float hn = sigmoid_f(zo)*tanhf(cn);
        if ((lane & 15) == 0){
          cown[i] = cn; hnew[i] = hn;
          int col = 32*k + i;
          st_rlx(h_all + (size_t)((t+1)*Bn + b)*Un + col, hn);
          if (b == 0) c0_all[(t+1)*Un + col] = cn;
        }
      }
    } else {
      int sw = w - 8;
      if (t > 0){
        float v = red64[lane];
        #pragma unroll
        for (int m = 1; m < 64; m <<= 1) v += __shfl_xor(v, m);
        float inv = 1.f / v;
        float clp = 0.f;
        #pragma unroll
        for (int j = 0; j < 7; ++j){
          int r = sw + 8*j;
          if (r < 50){
            float aa = ev_r[j] * inv;
            if (lane == 0)
              a_all[(size_t)((t-1)*Bn + b)*Sn + 50*k + r] = aa;
            clp += fminf(cov_r[j], aa);
            cov_r[j] += aa;
          }
        }
        if (lane == 0) atomicAdd(&covloss[b*Tn + (t-1)], clp);
      }
      const float4 da = *(const float4*)(dec_lds + lane*4);
      float wsum = 0.f;
      #pragma unroll
      for (int j = 0; j < 7; ++j){
        int r = sw + 8*j;
        if (r < 50){
          const float4 e = *(const float4*)(enc_attn + ((size_t)(b*Sn + 50*k + r))*AUn + lane*4);
          float cvv = cov_r[j];
          float psc = tanh_fast(e.x + cvv*wc4.x + da.x)*wa4.x
                    + tanh_fast(e.y + cvv*wc4.y + da.y)*wa4.y
                    + tanh_fast(e.z + cvv*wc4.z + da.z)*wa4.z
                    + tanh_fast(e.w + cvv*wc4.w + da.w)*wa4.w;
          #pragma unroll
          for (int m = 1; m < 64; m <<= 1) psc += __shfl_xor(psc, m);
          float ev = __expf(psc);
          ev_r[j] = ev;
          wsum += ev;
        }
      }
      if (lane == 0)
        st_rlx(spart2 + cur*(Bn*64) + b*64 + k*8 + sw, wsum);
    }
    __syncthreads();
    // P3: dec(t+1) on 256 threads
    if (tid < 256 && t + 1 < Tn){
      int c = tid;
      float acc = 0.f;
      const float* wdh = Wd + (size_t)(32*k)*AUn + c;
      #pragma unroll 8
      for (int u = 0; u < 32; ++u) acc += hnew[u]*wdh[(size_t)u*AUn];
      const float* wdc = Wd + (size_t)(Un + 32*k)*AUn + c;
      #pragma unroll 8
      for (int u = 0; u < 32; ++u) acc += cown[u]*wdc[(size_t)u*AUn];
      st_rlx(decp + (size_t)oth*(Bn*8*256) + (size_t)(b*8 + k)*256 + c, acc);
    }
    __syncthreads();    // drains all stores before flag
    if (tid == 0) st_flag(myflag, (unsigned)(t + 2));
  }

  // ======== post-loop: finalize softmax(Tn-1) ========
  if (tid < 8){
    while (ld_flag(flags + tid*32) < (unsigned)(Tn + 1))
      __builtin_amdgcn_s_sleep(1);
  }
  __syncthreads();
  if (tid < 64) red64[tid] = ld_rlx(spart2 + ((Tn-1)&1)*(Bn*64) + b*64 + tid);
  __syncthreads();
  if (w >= 8){
    int sw = w - 8;
    float v = red64[lane];
    #pragma unroll
    for (int m = 1; m < 64; m <<= 1) v += __shfl_xor(v, m);
    float inv = 1.f / v;
    float clp = 0.f;
    #pragma unroll
    for (int j = 0; j < 7; ++j){
      int r = sw + 8*j;
      if (r < 50){
        float aa = ev_r[j] * inv;
        if (lane == 0)
          a_all[(size_t)((Tn-1)*Bn + b)*Sn + 50*k + r] = aa;
        clp += fminf(cov_r[j], aa);
      }
    }
    if (lane == 0) atomicAdd(&covloss[b*Tn + (Tn-1)], clp);
  }
}

// ---------------- post-loop kernels ----------------

// hid = h_all @ W1 + b1 -> bf16    (block per t)
__global__ __launch_bounds__(256) void k_hid(const float* __restrict__ h_all,
    const float* __restrict__ W1, const float* __restrict__ b1, ushort_t* __restrict__ hid){
  __shared__ float hl[Bn*Un];
  int t = blockIdx.x, tid = threadIdx.x;
  for (int i = tid; i < Bn*Un; i += 256) hl[i] = h_all[(size_t)t*Bn*Un + i];
  __syncthreads();
  int j = tid;
  float bj = b1[j];
  float acc[32];
  #pragma unroll
  for (int r = 0; r < 32; ++r) acc[r] = bj;
  for (int u = 0; u < Un; ++u){
    float wv = W1[u*Un + j];
    #pragma unroll
    for (int r = 0; r < 32; ++r) acc[r] += hl[r*Un + u]*wv;
  }
  #pragma unroll
  for (int r = 0; r < 32; ++r) hid[(size_t)(t*Bn + r)*Un + j] = f2bf(acc[r]);
}

// pg[t] via row-0 quirk
__global__ __launch_bounds__(256) void k_pg(const float* __restrict__ a_all,
    const float* __restrict__ enc_out, const float* __restrict__ h_all,
    const float* __restrict__ c0_all, const float* __restrict__ gpWs,
    const float* __restrict__ gpWc, const float* __restrict__ gpx,
    const float* __restrict__ gpWg, float* __restrict__ pg){
  __shared__ float al[Sn];
  __shared__ float cv[ENCn];
  __shared__ float red[4];
  int t = blockIdx.x, tid = threadIdx.x;
  for (int s = tid; s < Sn; s += 256) al[s] = a_all[(size_t)(t*Bn + 0)*Sn + s];
  __syncthreads();
  for (int e = tid; e < ENCn; e += 256){
    float acc = 0.f;
    for (int s = 0; s < Sn; ++s) acc += enc_out[(size_t)s*ENCn + e]*al[s];
    cv[e] = acc;
  }
  __syncthreads();
  int j = tid;
  float g = gpx[t*GPn + j];
  const float* h0r = h_all + (size_t)t*Bn*Un;       // b = 0 row
  const float* c0r = c0_all + t*Un;
  for (int u = 0; u < Un; ++u) g += h0r[u]*gpWs[u*GPn + j];
  for (int u = 0; u < Un; ++u) g += c0r[u]*gpWs[(Un+u)*GPn + j];
  for (int e = 0; e < ENCn; ++e) g += cv[e]*gpWc[e*GPn + j];
  float v = g * gpWg[j];
  int lane = tid & 63, wv2 = tid >> 6;
  #pragma unroll
  for (int m = 1; m < 64; m <<= 1) v += __shfl_xor(v, m);
  if (lane == 0) red[wv2] = v;
  __syncthreads();
  if (tid == 0) pg[t] = 1.f/(1.f+__expf(-(red[0]+red[1]+red[2]+red[3])));
}

// GEMM (round-8 form): 128-row tiles, 512 threads, single-buffer staging.
// mode 0: Ssum[r] += sum_v exp(logit);  mode 1: probs = pg*exp/S (+OOV zeros) + amax
__global__ __launch_bounds__(512) void k_gemm(const ushort_t* __restrict__ A,
    const ushort_t* __restrict__ Bw, const float* __restrict__ b2,
    float* __restrict__ Ssum, u64* __restrict__ amax, const float* __restrict__ pg,
    float* __restrict__ probs, int mode){
  int r0 = blockIdx.x * 128;
  int n0 = blockIdx.y * 256;
  int tid = threadIdx.x;
  if (mode == 1 && n0 >= Vn){
    for (int idx = tid; idx < 128*OOVn; idx += 512){
      int i = idx/OOVn, vv = idx%OOVn;
      int r = r0+i; int tt = r>>5, bb = r&31;
      probs[(size_t)(bb*Tn+tt)*VEn + Vn + vv] = 0.f;
    }
    return;
  }
  __shared__ ushort_t Bs[64*264];          // [64 n][256 k + pad8]
  int lane = tid & 63, w = tid >> 6;       // 8 waves, 16 rows each
  bf16x8 af[8];
  {
    const ushort_t* ar = A + (size_t)(r0 + w*16 + (lane&15))*Un + (lane>>4)*8;
    #pragma unroll
    for (int kk = 0; kk < 8; ++kk) af[kk] = *(const bf16x8*)(ar + kk*32);
  }
  f32x4 acc[16];
  #pragma unroll
  for (int i = 0; i < 16; ++i) acc[i] = (f32x4){0.f,0.f,0.f,0.f};

  for (int nsub = 0; nsub < 4; ++nsub){
    __syncthreads();
    {
      const ushort_t* gb = Bw + (size_t)(n0 + nsub*64)*Un;
      #pragma unroll
      for (int i = 0; i < 4; ++i){
        int chunk = tid + i*512;
        int rr = chunk >> 5, cc = chunk & 31;
        uint4 d = *(const uint4*)(gb + rr*Un + cc*8);
        *(uint4*)(Bs + rr*264 + cc*8) = d;
      }
    }
    __syncthreads();
    #pragma unroll
    for (int kk = 0; kk < 8; ++kk){
      #pragma unroll
      for (int ntl = 0; ntl < 4; ++ntl){
        bf16x8 bf = *(const bf16x8*)(Bs + (ntl*16 + (lane&15))*264 + kk*32 + (lane>>4)*8);
        acc[nsub*4+ntl] = __builtin_amdgcn_mfma_f32_16x16x32_bf16(af[kk], bf, acc[nsub*4+ntl], 0, 0, 0);
      }
    }
  }

  int rowloc = w*16 + (lane>>4)*4;
  if (mode == 0){
    float rs[4] = {0.f,0.f,0.f,0.f};
    #pragma unroll
    for (int nt = 0; nt < 16; ++nt){
      int v = n0 + (nt>>2)*64 + (nt&3)*16 + (lane&15);
      float bb = b2[v];
      #pragma unroll
      for (int i = 0; i < 4; ++i) rs[i] += __expf(acc[nt][i] + bb);
    }
    #pragma unroll
    for (int m = 1; m < 16; m <<= 1)
      #pragma unroll
      for (int i = 0; i < 4; ++i) rs[i] += __shfl_xor(rs[i], m);
    if ((lane&15) == 0)
      #pragma unroll
      for (int i = 0; i < 4; ++i) atomicAdd(&Ssum[r0+rowloc+i], rs[i]);
  } else {
    float sc[4]; size_t obase[4];
    #pragma unroll
    for (int i = 0; i < 4; ++i){
      int r = r0+rowloc+i; int tt = r>>5, bb = r&31;
      sc[i] = pg[tt] / Ssum[r];
      obase[i] = (size_t)(bb*Tn+tt)*VEn;
    }
    u64 pm[4] = {0,0,0,0};
    #pragma unroll
    for (int nt = 0; nt < 16; ++nt){
      int v = n0 + (nt>>2)*64 + (nt&3)*16 + (lane&15);
      float bb = b2[v];
      #pragma unroll
      for (int i = 0; i < 4; ++i){
        float val = __expf(acc[nt][i] + bb) * sc[i];
        __builtin_nontemporal_store(val, &probs[obase[i] + v]);
        u64 p = ((u64)__float_as_uint(val)<<32) | (u64)(0xFFFFFFFFu - (unsigned)v);
        pm[i] = p > pm[i] ? p : pm[i];
      }
    }
    #pragma unroll
    for (int m = 1; m < 16; m <<= 1)
      #pragma unroll
      for (int i = 0; i < 4; ++i){
        u64 o = shfl_xor_u64(pm[i], m);
        pm[i] = o > pm[i] ? o : pm[i];
      }
    if ((lane&15) == 0)
      #pragma unroll
      for (int i = 0; i < 4; ++i) atomicMax(&amax[r0+rowloc+i], pm[i]);
  }
}

// scatter copy-dist into probs (deterministic deduped single-writer) + amax
__global__ __launch_bounds__(256) void k_scatter(const int* __restrict__ ext,
    const float* __restrict__ a_all, const float* __restrict__ pg,
    float* __restrict__ probs, u64* __restrict__ amax){
  __shared__ int tok[Sn];
  __shared__ float val[Sn];
  int r = blockIdx.x; int t = r>>5, b = r&31;
  float c1 = 1.f - pg[t];
  int tid = threadIdx.x;
  for (int s = tid; s < Sn; s += 256){
    tok[s] = ext[b*Sn + s];
    val[s] = c1 * a_all[(size_t)r*Sn + s];
  }
  __syncthreads();
  size_t obase = (size_t)(b*Tn + t)*VEn;
  for (int s = tid; s < Sn; s += 256){
    int tk = tok[s];
    bool leader = true;
    float tot = 0.f;
    for (int s2 = 0; s2 < Sn; ++s2){
      if (tok[s2] == tk){
        if (s2 < s){ leader = false; break; }
        tot += val[s2];
      }
    }
    if (leader){
      float nv = probs[obase + tk] + tot;
      probs[obase + tk] = nv;
      u64 p = ((u64)__float_as_uint(nv)<<32) | (u64)(0xFFFFFFFFu - (unsigned)tk);
      atomicMax(&amax[r], p);
    }
  }
}

__global__ __launch_bounds__(256) void k_seqout(const u64* __restrict__ amax,
    float* __restrict__ seqs){
  int r = blockIdx.x*256 + threadIdx.x;
  if (r >= Tn*Bn) return;
  int t = r>>5, b = r&31;
  unsigned tk = 0xFFFFFFFFu - (unsigned)(amax[r] & 0xFFFFFFFFull);
  seqs[b*Tn + t] = (float)tk;
}

// ---------------- host launch ----------------

extern "C" void kernel_launch(void* const* d_in, const int* in_sizes, int n_in,
                              void* d_out, int out_size, void* d_ws, size_t ws_size,
                              hipStream_t stream){
  (void)in_sizes; (void)n_in; (void)out_size; (void)ws_size;
  const int*   gt       = (const int*)d_in[0];
  const int*   ext      = (const int*)d_in[1];
  const float* enc_out  = (const float*)d_in[2];
  const float* enc_attn = (const float*)d_in[3];
  const float* h0       = (const float*)d_in[4];
  const float* c0       = (const float*)d_in[5];
  const float* emb      = (const float*)d_in[6];
  const float* Wk       = (const float*)d_in[7];
  const float* Wr       = (const float*)d_in[8];
  const float* lb       = (const float*)d_in[9];
  const float* Wd       = (const float*)d_in[10];
  const float* bd       = (const float*)d_in[11];
  const float* Wc       = (const float*)d_in[12];
  const float* Wa       = (const float*)d_in[13];
  const float* W1       = (const float*)d_in[14];
  const float* b1       = (const float*)d_in[15];
  const float* W2       = (const float*)d_in[16];
  const float* b2       = (const float*)d_in[17];
  const float* gpWs     = (const float*)d_in[18];
  const float* gpWc     = (const float*)d_in[19];
  const float* gpWi     = (const float*)d_in[20];
  const float* gpbi     = (const float*)d_in[21];
  const float* gpWg     = (const float*)d_in[22];

  float* probs   = (float*)d_out;
  float* seqs    = probs + (size_t)Bn*Tn*VEn;
  float* covloss = seqs + Bn*Tn;

  char* wp = (char*)d_ws;
  auto carve = [&](size_t bytes)->void*{
    void* p = (void*)wp; wp += (bytes + 255) & ~(size_t)255; return p;
  };
  float*    Xall    = (float*)carve((size_t)3200*En*4);
  float*    Zx      = (float*)carve((size_t)3200*Z4n*4);
  float*    gpx     = (float*)carve((size_t)Tn*GPn*4);
  float*    h_all   = (float*)carve((size_t)Tn*Bn*Un*4);
  float*    decp    = (float*)carve((size_t)2*Bn*8*256*4);
  float*    c0_all  = (float*)carve((size_t)Tn*Un*4);
  float*    a_all   = (float*)carve((size_t)3200*Sn*4);
  ushort_t* hid_bf  = (ushort_t*)carve((size_t)3200*Un*2);
  ushort_t* W2T     = (ushort_t*)carve((size_t)Vn*Un*2);
  float*    Ssum    = (float*)carve((size_t)3200*4);
  u64*      amax    = (u64*)carve((size_t)3200*8);
  float*    pg      = (float*)carve((size_t)Tn*4);
  float*    spart2  = (float*)carve((size_t)2*Bn*64*4);
  unsigned* bars    = (unsigned*)carve((size_t)Bn*8*32*4);

  hipMemsetAsync(Ssum, 0, 3200*4, stream);
  hipMemsetAsync(amax, 0, 3200*8, stream);
  hipMemsetAsync(bars, 0, Bn*8*32*4, stream);
  hipMemsetAsync(covloss, 0, Bn*Tn*4, stream);

  k_gather<<<3200, 256, 0, stream>>>(gt, emb, Xall);
  k_zx    <<<dim3(50,16), 256, 0, stream>>>(Xall, Wk, lb, Zx);

  k_loop  <<<256, 1024, 0, stream>>>(Zx, Wr, Wd, bd, Wc, Wa, enc_attn,
                                     h0, c0, h_all, decp, c0_all,
                                     a_all, covloss, spart2, bars);

  k_w2t <<<dim3(500,4), 256, 0, stream>>>(W2, W2T);
  k_gpx <<<Tn, 256, 0, stream>>>(Xall, gpWi, gpbi, gpx);
  k_hid <<<Tn, 256, 0, stream>>>(h_all, W1, b1, hid_bf);
  k_pg  <<<Tn, 256, 0, stream>>>(a_all, enc_out, h_all, c0_all, gpWs, gpWc, gpx, gpWg, pg);
  k_gemm<<<dim3(25,125), 512, 0, stream>>>(hid_bf, W2T, b2, Ssum, amax, pg, probs, 0);
  k_gemm<<<dim3(25,126), 512, 0, stream>>>(hid_bf, W2T, b2, Ssum, amax, pg, probs, 1);
  k_scatter<<<3200, 256, 0, stream>>>(ext, a_all, pg, probs, amax);
  k_seqout <<<13, 256, 0, stream>>>(amax, seqs);
}

// Round 12
// 1415.100 us; speedup vs baseline: 1.1491x; 1.1491x over previous
//
#include <hip/hip_runtime.h>
#include <hip/hip_bf16.h>

#define Bn 32
#define Sn 400
#define Tn 100
#define Vn 32000
#define OOVn 100
#define VEn 32100
#define En 512
#define Un 256
#define AUn 256
#define GPn 256
#define ENCn 512
#define Z4n 1024

typedef __attribute__((ext_vector_type(8))) short bf16x8;
typedef __attribute__((ext_vector_type(4))) float f32x4;
typedef unsigned short ushort_t;
typedef unsigned long long u64;

__device__ __forceinline__ float rcp_f(float x){ return __builtin_amdgcn_rcpf(x); }
__device__ __forceinline__ float tanh_fast(float x){
  float e2 = __expf(2.f*x);
  return 1.f - 2.f*rcp_f(e2 + 1.f);
}
__device__ __forceinline__ float sigmoid_f(float x){ return 1.f/(1.f+__expf(-x)); }
__device__ __forceinline__ ushort_t f2bf(float f){
  unsigned u = __float_as_uint(f);
  unsigned r = (u + 0x7FFFu + ((u>>16)&1u)) >> 16;   // RNE
  return (ushort_t)r;
}
__device__ __forceinline__ u64 shfl_xor_u64(u64 v, int m){
  unsigned lo = (unsigned)v, hi = (unsigned)(v>>32);
  lo = (unsigned)__shfl_xor((int)lo, m);
  hi = (unsigned)__shfl_xor((int)hi, m);
  return ((u64)hi<<32)|(u64)lo;
}

// relaxed agent-scope ops: coherence-point loads/stores, no cache maintenance
__device__ __forceinline__ void st_rlx(float* p, float v){
  __hip_atomic_store(p, v, __ATOMIC_RELAXED, __HIP_MEMORY_SCOPE_AGENT);
}
__device__ __forceinline__ float ld_rlx(const float* p){
  return __hip_atomic_load(p, __ATOMIC_RELAXED, __HIP_MEMORY_SCOPE_AGENT);
}
__device__ __forceinline__ void st_flag(unsigned* p, unsigned v){
  __hip_atomic_store(p, v, __ATOMIC_RELAXED, __HIP_MEMORY_SCOPE_AGENT);
}
__device__ __forceinline__ unsigned ld_flag(const unsigned* p){
  return __hip_atomic_load(p, __ATOMIC_RELAXED, __HIP_MEMORY_SCOPE_AGENT);
}

// ---------------- pre-loop: Zx = emb[gt] @ Wk + bias (fused gather) ----------------

__global__ __launch_bounds__(256) void k_zx(const int* __restrict__ gt,
    const float* __restrict__ emb, const float* __restrict__ Wk,
    const float* __restrict__ bias, float* __restrict__ Zx){
  __shared__ float As[64][17];
  __shared__ float Bs[16][65];
  __shared__ int tok_lds[64];
  int r0 = blockIdx.x * 64;
  int c0 = blockIdx.y * 64;
  int tid = threadIdx.x;
  int ty = tid >> 4, tx = tid & 15;
  if (tid < 64){
    int r = r0 + tid;
    tok_lds[tid] = gt[(r & 31)*Tn + (r >> 5)];
  }
  __syncthreads();
  float acc[4][4] = {};
  for (int k0 = 0; k0 < En; k0 += 16){
    #pragma unroll
    for (int p = 0; p < 4; ++p){
      int row = (tid>>4) + p*16, kk = tid & 15;
      As[row][kk] = emb[(size_t)tok_lds[row]*En + k0 + kk];
    }
    #pragma unroll
    for (int p = 0; p < 4; ++p){
      int kk = (tid>>6) + p*4, cc = tid & 63;
      Bs[kk][cc] = Wk[(size_t)(k0+kk)*Z4n + c0 + cc];
    }
    __syncthreads();
    #pragma unroll
    for (int kk = 0; kk < 16; ++kk){
      float av[4], bv[4];
      #pragma unroll
      for (int i=0;i<4;++i) av[i] = As[ty*4+i][kk];
      #pragma unroll
      for (int j=0;j<4;++j) bv[j] = Bs[kk][tx*4+j];
      #pragma unroll
      for (int i=0;i<4;++i)
        #pragma unroll
        for (int j=0;j<4;++j) acc[i][j] += av[i]*bv[j];
    }
    __syncthreads();
  }
  #pragma unroll
  for (int i=0;i<4;++i){
    int row = r0 + ty*4 + i;
    #pragma unroll
    for (int j=0;j<4;++j){
      int col = c0 + tx*4 + j;
      Zx[(size_t)row*Z4n + col] = acc[i][j] + bias[col];
    }
  }
}

// ---------------- persistent 256-block recurrent kernel (round-7 form) ----
// b = blockIdx&31, k = blockIdx>>5. ONE flag per step. Deferred softmax:
// block k owns s-rows [50k,50k+50) with LOCAL cov + unnormalized exp; the
// 8 partial sums (spart) published at the step flag are consumed next step.

__global__ __launch_bounds__(1024, 1) void k_loop(
    const float* __restrict__ Zx, const float* __restrict__ Wr,
    const float* __restrict__ Wd, const float* __restrict__ bd,
    const float* __restrict__ Wc, const float* __restrict__ Wa,
    const float* __restrict__ enc_attn,
    const float* __restrict__ h0, const float* __restrict__ c0,
    float* __restrict__ h_all, float* __restrict__ decp,
    float* __restrict__ c0_all, float* __restrict__ a_all,
    float* __restrict__ covloss, float* __restrict__ spart,
    unsigned* __restrict__ bars){
  __shared__ float Wr_lds[256*128];     // 128 KB: Wr cols {32k+i+256q}
  __shared__ float hfull[Un];
  __shared__ float ppart[8][132];
  __shared__ float zx_lds[128];
  __shared__ float zfull[128];
  __shared__ float hnew[32], cown[32];
  __shared__ float dec_lds[AUn];
  __shared__ float cov_lds[50], sc_lds[50];
  __shared__ float wred[16];
  __shared__ float red8[8];

  const int b = blockIdx.x & 31, k = blockIdx.x >> 5;
  const int tid = threadIdx.x, lane = tid & 63, w = tid >> 6;
  unsigned* flags = bars + b*8*32;          // 8 slots, 128 B apart
  unsigned* myflag = flags + k*32;

  for (int idx = tid; idx < 256*128; idx += 1024){
    int u = idx >> 7, jl = idx & 127;
    int gcol = 32*k + (jl & 31) + 256*(jl >> 5);
    Wr_lds[idx] = Wr[(size_t)u*Z4n + gcol];
  }
  if (tid < 32) cown[tid] = c0[b*Un + 32*k + tid];
  if (tid < 50) cov_lds[tid] = 0.f;
  const float4 wc4 = *(const float4*)(Wc + lane*4);
  const float4 wa4 = *(const float4*)(Wa + lane*4);
  if (tid < 256) hfull[tid] = h0[b*Un + tid];
  if (tid >= 256 && tid < 384){
    int jl = tid - 256;
    int gcol = 32*k + (jl & 31) + 256*(jl >> 5);
    zx_lds[jl] = Zx[(size_t)(0*Bn + b)*Z4n + gcol];
  }
  __syncthreads();

  // ======== prestep: h(0), c(0), decp(0), flag = 1 ========
  {
    int p = tid >> 7, jl = tid & 127;
    float acc = 0.f;
    const float* wr = Wr_lds + (p*32)*128 + jl;
    const float* hb = hfull + p*32;
    #pragma unroll 8
    for (int uu = 0; uu < 32; ++uu) acc += hb[uu]*wr[uu*128];
    ppart[p][jl] = acc;
  }
  __syncthreads();
  if (tid < 128){
    float s = zx_lds[tid];
    #pragma unroll
    for (int q = 0; q < 8; ++q) s += ppart[q][tid];
    zfull[tid] = s;
  }
  __syncthreads();
  if (tid < 32){
    float zi = zfull[tid], zf = zfull[32+tid], zg = zfull[64+tid], zo = zfull[96+tid];
    float cn = sigmoid_f(zf)*cown[tid] + sigmoid_f(zi)*tanhf(zg);
    float hn = sigmoid_f(zo)*tanhf(cn);
    cown[tid] = cn; hnew[tid] = hn;
    int col = 32*k + tid;
    st_rlx(h_all + (size_t)(0*Bn + b)*Un + col, hn);
    if (b == 0) c0_all[0*Un + col] = cn;
  }
  __syncthreads();
  if (tid < 256){
    int c = tid;
    float acc = 0.f;
    const float* wdh = Wd + (size_t)(32*k)*AUn + c;
    #pragma unroll 8
    for (int u = 0; u < 32; ++u) acc += hnew[u]*wdh[(size_t)u*AUn];
    const float* wdc = Wd + (size_t)(Un + 32*k)*AUn + c;
    #pragma unroll 8
    for (int u = 0; u < 32; ++u) acc += cown[u]*wdc[(size_t)u*AUn];
    st_rlx(decp + (size_t)(b*8 + k)*256 + c, acc);   // slot 0
  }
  __syncthreads();    // drains vmcnt: stores acknowledged
  if (tid == 0) st_flag(myflag, 1u);

  // ======== main loop ========
  for (int t = 0; t < Tn; ++t){
    const int cur = t & 1, oth = cur ^ 1;
    // P0: wait (covers h(t), decp(t), spart(t-1))
    if (tid < 8){
      while (ld_flag(flags + tid*32) < (unsigned)(t+1))
        __builtin_amdgcn_s_sleep(1);
    }
    __syncthreads();
    // P1: all cross-block loads, one latency
    if (tid < 256){
      hfull[tid] = ld_rlx(h_all + (size_t)(t*Bn + b)*Un + tid);
    } else if (tid < 512){
      int c = tid - 256;
      float s = bd[c];
      const float* dp = decp + (size_t)cur*(Bn*8*256) + (size_t)(b*8)*256 + c;
      #pragma unroll
      for (int q = 0; q < 8; ++q) s += ld_rlx(dp + q*256);
      dec_lds[c] = s;
    } else if (tid < 520){
      red8[tid-512] = (t > 0) ? ld_rlx(spart + oth*(Bn*8) + b*8 + (tid-512)) : 0.f;
    } else if (tid >= 576 && tid < 704 && t + 1 < Tn){
      int jl = tid - 576;
      int gcol = 32*k + (jl & 31) + 256*(jl >> 5);
      zx_lds[jl] = Zx[(size_t)((t+1)*Bn + b)*Z4n + gcol];
    }
    __syncthreads();
    // P2: softmax-finish(t-1) on wave 0 ; LSTM partials on all waves
    if (t > 0 && w == 0){
      float pv = (lane < 8) ? red8[lane] : 0.f;
      pv += __shfl_xor(pv, 1); pv += __shfl_xor(pv, 2); pv += __shfl_xor(pv, 4);
      float inv = 1.f / __shfl(pv, 0);
      float clp = 0.f;
      if (lane < 50){
        float aa = sc_lds[lane] * inv;
        float co = cov_lds[lane];
        a_all[(size_t)((t-1)*Bn + b)*Sn + 50*k + lane] = aa;
        clp = fminf(co, aa);
        cov_lds[lane] = co + aa;
      }
      #pragma unroll
      for (int m = 1; m < 64; m <<= 1) clp += __shfl_xor(clp, m);
      if (lane == 0) atomicAdd(&covloss[b*Tn + (t-1)], clp);
    }
    {
      int p = tid >> 7, jl = tid & 127;
      float acc = 0.f;
      const float* wr = Wr_lds + (p*32)*128 + jl;
      const float* hb = hfull + p*32;
      #pragma unroll 8
      for (int uu = 0; uu < 32; ++uu) acc += hb[uu]*wr[uu*128];
      ppart[p][jl] = acc;
    }
    __syncthreads();
    // P3: z reduce
    if (tid < 128 && t + 1 < Tn){
      float s = zx_lds[tid];
      #pragma unroll
      for (int q = 0; q < 8; ++q) s += ppart[q][tid];
      zfull[tid] = s;
    }
    __syncthreads();
    // P4: gates + h(t+1)/c publish
    if (tid < 32 && t + 1 < Tn){
      float zi = zfull[tid], zf = zfull[32+tid], zg = zfull[64+tid], zo = zfull[96+tid];
      float cn = sigmoid_f(zf)*cown[tid] + sigmoid_f(zi)*tanhf(zg);
      float hn = sigmoid_f(zo)*tanhf(cn);
      cown[tid] = cn; hnew[tid] = hn;
      int col = 32*k + tid;
      st_rlx(h_all + (size_t)((t+1)*Bn + b)*Un + col, hn);
      if (b == 0) c0_all[(t+1)*Un + col] = cn;
    }
    __syncthreads();
    // P5: decp(t+1) on waves 0-3 ; scores(t) on waves 4-15 (overlaps store-ack)
    if (w < 4){
      if (t + 1 < Tn){
        int c = tid;
        float acc = 0.f;
        const float* wdh = Wd + (size_t)(32*k)*AUn + c;
        #pragma unroll 8
        for (int u = 0; u < 32; ++u) acc += hnew[u]*wdh[(size_t)u*AUn];
        const float* wdc = Wd + (size_t)(Un + 32*k)*AUn + c;
        #pragma unroll 8
        for (int u = 0; u < 32; ++u) acc += cown[u]*wdc[(size_t)u*AUn];
        st_rlx(decp + (size_t)oth*(Bn*8*256) + (size_t)(b*8 + k)*256 + c, acc);
      }
    } else {
      const float4 da = *(const float4*)(dec_lds + lane*4);
      float wsum = 0.f;
      for (int sl = w - 4; sl < 50; sl += 12){
        float cvv = cov_lds[sl];
        const float4 e = *(const float4*)(enc_attn + ((size_t)(b*Sn + 50*k + sl))*AUn + lane*4);
        float psc = tanh_fast(e.x + cvv*wc4.x + da.x)*wa4.x
                  + tanh_fast(e.y + cvv*wc4.y + da.y)*wa4.y
                  + tanh_fast(e.z + cvv*wc4.z + da.z)*wa4.z
                  + tanh_fast(e.w + cvv*wc4.w + da.w)*wa4.w;
        #pragma unroll
        for (int m = 1; m < 64; m <<= 1) psc += __shfl_xor(psc, m);
        if (lane == 0){
          float ev = __expf(psc);
          sc_lds[sl] = ev;
          wsum += ev;
        }
      }
      if (lane == 0) wred[w] = wsum;
    }
    __syncthreads();
    // P6: spart publish + flag
    if (tid == 0){
      float S = 0.f;
      #pragma unroll
      for (int q = 4; q < 16; ++q) S += wred[q];
      st_rlx(spart + cur*(Bn*8) + b*8 + k, S);
    }
    __syncthreads();    // drains all stores (incl. spart) before flag
    if (tid == 0) st_flag(myflag, (unsigned)(t + 2));
  }

  // ======== post-loop: softmax-finish(Tn-1) ========
  if (tid < 8){
    while (ld_flag(flags + tid*32) < (unsigned)(Tn + 1))
      __builtin_amdgcn_s_sleep(1);
  }
  __syncthreads();
  if (tid < 8) red8[tid] = ld_rlx(spart + ((Tn-1)&1)*(Bn*8) + b*8 + tid);
  __syncthreads();
  if (w == 0){
    float pv = (lane < 8) ? red8[lane] : 0.f;
    pv += __shfl_xor(pv, 1); pv += __shfl_xor(pv, 2); pv += __shfl_xor(pv, 4);
    float inv = 1.f / __shfl(pv, 0);
    float clp = 0.f;
    if (lane < 50){
      float aa = sc_lds[lane] * inv;
      float co = cov_lds[lane];
      a_all[(size_t)((Tn-1)*Bn + b)*Sn + 50*k + lane] = aa;
      clp = fminf(co, aa);
    }
    #pragma unroll
    for (int m = 1; m < 64; m <<= 1) clp += __shfl_xor(clp, m);
    if (lane == 0) atomicAdd(&covloss[b*Tn + (Tn-1)], clp);
  }
}

// ---------------- merged post-loop small kernels ----------------
// bid < 2000            : W2 transpose -> W2T bf16
// 2000 <= bid < 2100    : hid[t] = h_all[t] @ W1 + b1 -> bf16
// 2100 <= bid < 2200    : pg[t] (row-0 quirk, gpx inline)

__global__ __launch_bounds__(256) void k_misc(
    const float* __restrict__ W2, ushort_t* __restrict__ W2T,
    const float* __restrict__ h_all, const float* __restrict__ W1,
    const float* __restrict__ b1, ushort_t* __restrict__ hid,
    const int* __restrict__ gt, const float* __restrict__ emb,
    const float* __restrict__ gpWi, const float* __restrict__ gpbi,
    const float* __restrict__ a_all, const float* __restrict__ enc_out,
    const float* __restrict__ c0_all, const float* __restrict__ gpWs,
    const float* __restrict__ gpWc, const float* __restrict__ gpWg,
    float* __restrict__ pg){
  __shared__ __align__(16) char sbuf[32768];
  int bid = blockIdx.x, tid = threadIdx.x;
  if (bid < 2000){
    float (*tile)[65] = (float(*)[65])sbuf;
    int n0 = (bid % 500) * 64, k0 = (bid / 500) * 64;
    int tx = tid & 63, ty4 = tid >> 6;
    #pragma unroll
    for (int i = 0; i < 16; ++i){
      int kk = ty4 + i*4;
      tile[kk][tx] = W2[(size_t)(k0+kk)*Vn + n0 + tx];
    }
    __syncthreads();
    #pragma unroll
    for (int i = 0; i < 16; ++i){
      int n = ty4 + i*4;
      W2T[(size_t)(n0+n)*Un + k0 + tx] = f2bf(tile[tx][n]);
    }
  } else if (bid < 2100){
    float* hl = (float*)sbuf;          // 8192 floats
    int t = bid - 2000;
    for (int i = tid; i < Bn*Un; i += 256) hl[i] = h_all[(size_t)t*Bn*Un + i];
    __syncthreads();
    int j = tid;
    float bj = b1[j];
    float acc[32];
    #pragma unroll
    for (int r = 0; r < 32; ++r) acc[r] = bj;
    for (int u = 0; u < Un; ++u){
      float wv = W1[u*Un + j];
      #pragma unroll
      for (int r = 0; r < 32; ++r) acc[r] += hl[r*Un + u]*wv;
    }
    #pragma unroll
    for (int r = 0; r < 32; ++r) hid[(size_t)(t*Bn + r)*Un + j] = f2bf(acc[r]);
  } else {
    int t = bid - 2100;
    float* al  = (float*)sbuf;         // 400
    float* cv  = al + 400;             // 512
    float* xl  = cv + 512;             // 512
    float* red = xl + 512;             // 4
    for (int s = tid; s < Sn; s += 256) al[s] = a_all[(size_t)(t*Bn)*Sn + s];
    for (int i = tid; i < En; i += 256) xl[i] = emb[(size_t)gt[t]*En + i];
    __syncthreads();
    for (int e = tid; e < ENCn; e += 256){
      float acc = 0.f;
      for (int s = 0; s < Sn; ++s) acc += enc_out[(size_t)s*ENCn + e]*al[s];
      cv[e] = acc;
    }
    __syncthreads();
    int j = tid;
    float g = gpbi[j];
    for (int u = 0; u < En; ++u) g += xl[u]*gpWi[u*GPn + j];
    const float* h0r = h_all + (size_t)t*Bn*Un;       // b = 0 row
    const float* c0r = c0_all + t*Un;
    for (int u = 0; u < Un; ++u) g += h0r[u]*gpWs[u*GPn + j];
    for (int u = 0; u < Un; ++u) g += c0r[u]*gpWs[(Un+u)*GPn + j];
    for (int e = 0; e < ENCn; ++e) g += cv[e]*gpWc[e*GPn + j];
    float v = g * gpWg[j];
    int lane = tid & 63, wv2 = tid >> 6;
    #pragma unroll
    for (int m = 1; m < 64; m <<= 1) v += __shfl_xor(v, m);
    if (lane == 0) red[wv2] = v;
    __syncthreads();
    if (tid == 0) pg[t] = 1.f/(1.f+__expf(-(red[0]+red[1]+red[2]+red[3])));
  }
}

// GEMM (round-8 form): 128-row tiles, 512 threads, single-buffer staging.
// mode 0: Ssum[r] += sum_v exp(logit);  mode 1: probs = pg*exp/S (+OOV zeros) + amax
__global__ __launch_bounds__(512) void k_gemm(const ushort_t* __restrict__ A,
    const ushort_t* __restrict__ Bw, const float* __restrict__ b2,
    float* __restrict__ Ssum, u64* __restrict__ amax, const float* __restrict__ pg,
    float* __restrict__ probs, int mode){
  int r0 = blockIdx.x * 128;
  int n0 = blockIdx.y * 256;
  int tid = threadIdx.x;
  if (mode == 1 && n0 >= Vn){
    for (int idx = tid; idx < 128*OOVn; idx += 512){
      int i = idx/OOVn, vv = idx%OOVn;
      int r = r0+i; int tt = r>>5, bb = r&31;
      probs[(size_t)(bb*Tn+tt)*VEn + Vn + vv] = 0.f;
    }
    return;
  }
  __shared__ ushort_t Bs[64*264];          // [64 n][256 k + pad8]
  int lane = tid & 63, w = tid >> 6;       // 8 waves, 16 rows each
  bf16x8 af[8];
  {
    const ushort_t* ar = A + (size_t)(r0 + w*16 + (lane&15))*Un + (lane>>4)*8;
    #pragma unroll
    for (int kk = 0; kk < 8; ++kk) af[kk] = *(const bf16x8*)(ar + kk*32);
  }
  f32x4 acc[16];
  #pragma unroll
  for (int i = 0; i < 16; ++i) acc[i] = (f32x4){0.f,0.f,0.f,0.f};

  for (int nsub = 0; nsub < 4; ++nsub){
    __syncthreads();
    {
      const ushort_t* gb = Bw + (size_t)(n0 + nsub*64)*Un;
      #pragma unroll
      for (int i = 0; i < 4; ++i){
        int chunk = tid + i*512;
        int rr = chunk >> 5, cc = chunk & 31;
        uint4 d = *(const uint4*)(gb + rr*Un + cc*8);
        *(uint4*)(Bs + rr*264 + cc*8) = d;
      }
    }
    __syncthreads();
    #pragma unroll
    for (int kk = 0; kk < 8; ++kk){
      #pragma unroll
      for (int ntl = 0; ntl < 4; ++ntl){
        bf16x8 bf = *(const bf16x8*)(Bs + (ntl*16 + (lane&15))*264 + kk*32 + (lane>>4)*8);
        acc[nsub*4+ntl] = __builtin_amdgcn_mfma_f32_16x16x32_bf16(af[kk], bf, acc[nsub*4+ntl], 0, 0, 0);
      }
    }
  }

  int rowloc = w*16 + (lane>>4)*4;
  if (mode == 0){
    float rs[4] = {0.f,0.f,0.f,0.f};
    #pragma unroll
    for (int nt = 0; nt < 16; ++nt){
      int v = n0 + (nt>>2)*64 + (nt&3)*16 + (lane&15);
      float bb = b2[v];
      #pragma unroll
      for (int i = 0; i < 4; ++i) rs[i] += __expf(acc[nt][i] + bb);
    }
    #pragma unroll
    for (int m = 1; m < 16; m <<= 1)
      #pragma unroll
      for (int i = 0; i < 4; ++i) rs[i] += __shfl_xor(rs[i], m);
    if ((lane&15) == 0)
      #pragma unroll
      for (int i = 0; i < 4; ++i) atomicAdd(&Ssum[r0+rowloc+i], rs[i]);
  } else {
    float sc[4]; size_t obase[4];
    #pragma unroll
    for (int i = 0; i < 4; ++i){
      int r = r0+rowloc+i; int tt = r>>5, bb = r&31;
      sc[i] = pg[tt] / Ssum[r];
      obase[i] = (size_t)(bb*Tn+tt)*VEn;
    }
    u64 pm[4] = {0,0,0,0};
    #pragma unroll
    for (int nt = 0; nt < 16; ++nt){
      int v = n0 + (nt>>2)*64 + (nt&3)*16 + (lane&15);
      float bb = b2[v];
      #pragma unroll
      for (int i = 0; i < 4; ++i){
        float val = __expf(acc[nt][i] + bb) * sc[i];
        __builtin_nontemporal_store(val, &probs[obase[i] + v]);
        u64 p = ((u64)__float_as_uint(val)<<32) | (u64)(0xFFFFFFFFu - (unsigned)v);
        pm[i] = p > pm[i] ? p : pm[i];
      }
    }
    #pragma unroll
    for (int m = 1; m < 16; m <<= 1)
      #pragma unroll
      for (int i = 0; i < 4; ++i){
        u64 o = shfl_xor_u64(pm[i], m);
        pm[i] = o > pm[i] ? o : pm[i];
      }
    if ((lane&15) == 0)
      #pragma unroll
      for (int i = 0; i < 4; ++i) atomicMax(&amax[r0+rowloc+i], pm[i]);
  }
}

// deterministic deduped scatter + fused argmax -> seqs (atomicMax-return)
__global__ __launch_bounds__(256) void k_scatter(const int* __restrict__ ext,
    const float* __restrict__ a_all, const float* __restrict__ pg,
    float* __restrict__ probs, u64* __restrict__ amax, float* __restrict__ seqs){
  __shared__ int tok[Sn];
  __shared__ float val[Sn];
  __shared__ u64 wmax[4];
  int r = blockIdx.x; int t = r>>5, b = r&31;
  float c1 = 1.f - pg[t];
  int tid = threadIdx.x;
  for (int s = tid; s < Sn; s += 256){
    tok[s] = ext[b*Sn + s];
    val[s] = c1 * a_all[(size_t)r*Sn + s];
  }
  __syncthreads();
  size_t obase = (size_t)(b*Tn + t)*VEn;
  u64 pm = 0;
  for (int s = tid; s < Sn; s += 256){
    int tk = tok[s];
    bool leader = true;
    float tot = 0.f;
    for (int s2 = 0; s2 < Sn; ++s2){
      if (tok[s2] == tk){
        if (s2 < s){ leader = false; break; }
        tot += val[s2];
      }
    }
    if (leader){
      float nv = probs[obase + tk] + tot;
      probs[obase + tk] = nv;
      u64 p = ((u64)__float_as_uint(nv)<<32) | (u64)(0xFFFFFFFFu - (unsigned)tk);
      pm = p > pm ? p : pm;
    }
  }
  #pragma unroll
  for (int m = 1; m < 64; m <<= 1){
    u64 o = shfl_xor_u64(pm, m);
    pm = o > pm ? o : pm;
  }
  int lane = tid & 63, w = tid >> 6;
  if (lane == 0) wmax[w] = pm;
  __syncthreads();
  if (tid == 0){
    u64 mm = wmax[0];
    #pragma unroll
    for (int q = 1; q < 4; ++q) mm = wmax[q] > mm ? wmax[q] : mm;
    u64 old = atomicMax(&amax[r], mm);   // vocab-part max from gemm1
    u64 fin = old > mm ? old : mm;
    unsigned tk = 0xFFFFFFFFu - (unsigned)(fin & 0xFFFFFFFFull);
    seqs[b*Tn + t] = (float)tk;
  }
}

// ---------------- host launch ----------------

extern "C" void kernel_launch(void* const* d_in, const int* in_sizes, int n_in,
                              void* d_out, int out_size, void* d_ws, size_t ws_size,
                              hipStream_t stream){
  (void)in_sizes; (void)n_in; (void)out_size; (void)ws_size;
  const int*   gt       = (const int*)d_in[0];
  const int*   ext      = (const int*)d_in[1];
  const float* enc_out  = (const float*)d_in[2];
  const float* enc_attn = (const float*)d_in[3];
  const float* h0       = (const float*)d_in[4];
  const float* c0       = (const float*)d_in[5];
  const float* emb      = (const float*)d_in[6];
  const float* Wk       = (const float*)d_in[7];
  const float* Wr       = (const float*)d_in[8];
  const float* lb       = (const float*)d_in[9];
  const float* Wd       = (const float*)d_in[10];
  const float* bd       = (const float*)d_in[11];
  const float* Wc       = (const float*)d_in[12];
  const float* Wa       = (const float*)d_in[13];
  const float* W1       = (const float*)d_in[14];
  const float* b1       = (const float*)d_in[15];
  const float* W2       = (const float*)d_in[16];
  const float* b2       = (const float*)d_in[17];
  const float* gpWs     = (const float*)d_in[18];
  const float* gpWc     = (const float*)d_in[19];
  const float* gpWi     = (const float*)d_in[20];
  const float* gpbi     = (const float*)d_in[21];
  const float* gpWg     = (const float*)d_in[22];

  float* probs   = (float*)d_out;
  float* seqs    = probs + (size_t)Bn*Tn*VEn;
  float* covloss = seqs + Bn*Tn;

  char* wp = (char*)d_ws;
  auto carve = [&](size_t bytes)->void*{
    void* p = (void*)wp; wp += (bytes + 255) & ~(size_t)255; return p;
  };
  float*    Zx      = (float*)carve((size_t)3200*Z4n*4);
  float*    h_all   = (float*)carve((size_t)Tn*Bn*Un*4);
  float*    decp    = (float*)carve((size_t)2*Bn*8*256*4);
  float*    c0_all  = (float*)carve((size_t)Tn*Un*4);
  float*    a_all   = (float*)carve((size_t)3200*Sn*4);
  ushort_t* hid_bf  = (ushort_t*)carve((size_t)3200*Un*2);
  ushort_t* W2T     = (ushort_t*)carve((size_t)Vn*Un*2);
  float*    Ssum    = (float*)carve((size_t)3200*4);
  u64*      amax    = (u64*)carve((size_t)3200*8);
  float*    pg      = (float*)carve((size_t)Tn*4);
  float*    spart   = (float*)carve((size_t)2*Bn*8*4);
  unsigned* bars    = (unsigned*)carve((size_t)Bn*8*32*4);

  hipMemsetAsync(Ssum, 0, 3200*4, stream);
  hipMemsetAsync(amax, 0, 3200*8, stream);
  hipMemsetAsync(bars, 0, Bn*8*32*4, stream);
  hipMemsetAsync(covloss, 0, Bn*Tn*4, stream);

  k_zx  <<<dim3(50,16), 256, 0, stream>>>(gt, emb, Wk, lb, Zx);

  k_loop<<<256, 1024, 0, stream>>>(Zx, Wr, Wd, bd, Wc, Wa, enc_attn,
                                   h0, c0, h_all, decp, c0_all,
                                   a_all, covloss, spart, bars);

  k_misc<<<2200, 256, 0, stream>>>(W2, W2T, h_all, W1, b1, hid_bf,
                                   gt, emb, gpWi, gpbi, a_all, enc_out,
                                   c0_all, gpWs, gpWc, gpWg, pg);
  k_gemm<<<dim3(25,125), 512, 0, stream>>>(hid_bf, W2T, b2, Ssum, amax, pg, probs, 0);
  k_gemm<<<dim3(25,126), 512, 0, stream>>>(hid_bf, W2T, b2, Ssum, amax, pg, probs, 1);
  k_scatter<<<3200, 256, 0, stream>>>(ext, a_all, pg, probs, amax, seqs);
}